// Round 4
// baseline (336.782 us; speedup 1.0000x reference)
//
#include <hip/hip_runtime.h>
#include <hip/hip_bf16.h>
#include <stdint.h>

#define IN_F 512
#define H1_F 256
#define H2_F 128
#define MPAD 20096   // 157*128, padded row count for 128-row GEMM tiles

typedef __attribute__((ext_vector_type(8))) short short8;   // 8 bf16 (4 VGPRs)
typedef __attribute__((ext_vector_type(4))) float f32x4;
typedef __attribute__((ext_vector_type(4))) uint32_t u32x4;

// ---- fp32 -> (bf16 main | bf16 residual) packed in one u32 ----
__device__ inline uint32_t pack_hl(float x) {
    __hip_bfloat16 m = __float2bfloat16(x);
    float mf = __bfloat162float(m);
    __hip_bfloat16 r = __float2bfloat16(x - mf);
    return (uint32_t)__builtin_bit_cast(unsigned short, m) |
           ((uint32_t)__builtin_bit_cast(unsigned short, r) << 16);
}

__device__ inline float bf_lo(uint32_t v) { return __builtin_bit_cast(float, v << 16); }
__device__ inline float bf_hi(uint32_t v) { return __builtin_bit_cast(float, v & 0xffff0000u); }

__device__ inline void gld_lds16(const uint32_t* g, uint32_t* l) {
    __builtin_amdgcn_global_load_lds((const __attribute__((address_space(1))) uint32_t*)g,
                                     (__attribute__((address_space(3))) uint32_t*)l,
                                     16, 0, 0);
}

// ---------------- pass 1: privatized (x4) atomics ----------------
// out_pk4 bits [39:0] = sum w*2^24 fixed point; bits [63:40] = count
__global__ void count_kernel(const float* __restrict__ ew, const int* __restrict__ src,
                             const int* __restrict__ dst,
                             unsigned long long* __restrict__ out_pk4,
                             int* __restrict__ in_cnt4, int* __restrict__ slot, int E) {
    int stride = gridDim.x * blockDim.x;
    int c = threadIdx.x & 3;
    for (int e = blockIdx.x * blockDim.x + threadIdx.x; e < E; e += stride) {
        float w = ew[e];
        unsigned long long v = (1ULL << 40) |
            (unsigned long long)__float2uint_rn(w * 16777216.0f);
        atomicAdd(&out_pk4[(size_t)src[e] * 4 + c], v);
        int intra = atomicAdd(&in_cnt4[(size_t)dst[e] * 4 + c], 1);
        slot[e] = (c << 28) | intra;
    }
}

// ---------------- merged: unpack x4 copies + per-copy bases + exclusive scan ----------------
__global__ void scan_kernel(const unsigned long long* __restrict__ out_pk4,
                            const int* __restrict__ in_cnt4,
                            int* __restrict__ out_cnt, float* __restrict__ out_rs,
                            int* __restrict__ cbase4, int* __restrict__ in_cnt,
                            int* __restrict__ row_start, int n) {
    __shared__ int ls[1024];
    const unsigned long long M40 = (1ULL << 40) - 1;
    int tid = threadIdx.x;
    int chunk = (n + 1023) >> 10;
    int begin = tid * chunk;
    int end = begin + chunk; if (end > n) end = n;
    int ssum = 0;
    for (int i = begin; i < end; ++i) {
        unsigned long long lo = 0; int oc = 0;
#pragma unroll
        for (int c = 0; c < 4; ++c) {
            unsigned long long o = out_pk4[(size_t)i * 4 + c];
            lo += o & M40;
            oc += (int)(o >> 40);
        }
        out_cnt[i] = oc;
        out_rs[i] = (oc > 0) ? rsqrtf((float)lo * (1.0f / 16777216.0f)) : 0.f;
        int c0 = in_cnt4[(size_t)i * 4 + 0], c1 = in_cnt4[(size_t)i * 4 + 1];
        int c2 = in_cnt4[(size_t)i * 4 + 2], c3 = in_cnt4[(size_t)i * 4 + 3];
        cbase4[(size_t)i * 4 + 0] = 0;
        cbase4[(size_t)i * 4 + 1] = c0;
        cbase4[(size_t)i * 4 + 2] = c0 + c1;
        cbase4[(size_t)i * 4 + 3] = c0 + c1 + c2;
        int cnt = c0 + c1 + c2 + c3;
        in_cnt[i] = cnt;
        ssum += cnt;
    }
    ls[tid] = ssum;
    __syncthreads();
    for (int d = 1; d < 1024; d <<= 1) {
        int v = (tid >= d) ? ls[tid - d] : 0;
        __syncthreads();
        ls[tid] += v;
        __syncthreads();
    }
    int run = ls[tid] - ssum;
    for (int i = begin; i < end; ++i) {
        row_start[i] = run;
        run += in_cnt[i];
    }
}

// ---------------- pass 2: atomic-free bucket write (src|ew packed u64) ----------------
__global__ void scatter2_kernel(const float* __restrict__ ew, const int* __restrict__ src,
                                const int* __restrict__ dst,
                                const int* __restrict__ row_start, const int* __restrict__ cbase4,
                                const int* __restrict__ slot,
                                unsigned long long* __restrict__ s_meta, int E) {
    int stride = gridDim.x * blockDim.x;
    for (int e = blockIdx.x * blockDim.x + threadIdx.x; e < E; e += stride) {
        int d = dst[e];
        int sl = slot[e];
        int p = row_start[d] + cbase4[(size_t)d * 4 + (sl >> 28)] + (sl & 0x0FFFFFFF);
        unsigned long long m = (unsigned long long)(unsigned)src[e] |
            ((unsigned long long)__builtin_bit_cast(unsigned, ew[e]) << 32);
        s_meta[p] = m;
    }
}

// ---------------- per-node: in_wsum segment sum + s_pk = (src | nw<<32) ----------------
__global__ void in_finalize(const unsigned long long* __restrict__ s_meta,
                            const float* __restrict__ out_rs,
                            const int* __restrict__ row_start, const int* __restrict__ in_cnt,
                            unsigned long long* __restrict__ s_pk, int N) {
    int node = blockIdx.x;
    int lane = threadIdx.x;
    int start = row_start[node], cnt = in_cnt[node];
    float sum = 0.f;
    for (int j = lane; j < cnt; j += 64)
        sum += __builtin_bit_cast(float, (unsigned)(s_meta[start + j] >> 32));
    for (int d = 1; d < 64; d <<= 1) sum += __shfl_xor(sum, d);
    float rin = (cnt > 0) ? rsqrtf(sum) : 0.f;
    for (int j = lane; j < cnt; j += 64) {
        unsigned long long m = s_meta[start + j];
        int s = (int)(unsigned)m;
        float w = __builtin_bit_cast(float, (unsigned)(m >> 32));
        float nw = w * out_rs[s] * rin;
        s_pk[start + j] = (unsigned long long)(unsigned)s |
                          ((unsigned long long)__builtin_bit_cast(unsigned, nw) << 32);
    }
}

// ---------------- pack fp32 matrix -> hi/lo bf16 u32 (row-major) ----------------
__global__ void pack_rows(const float4* __restrict__ X, u32x4* __restrict__ P, int n4) {
    int stride = gridDim.x * blockDim.x;
    for (int i = blockIdx.x * blockDim.x + threadIdx.x; i < n4; i += stride) {
        float4 x = X[i];
        u32x4 o;
        o.x = pack_hl(x.x); o.y = pack_hl(x.y);
        o.z = pack_hl(x.z); o.w = pack_hl(x.w);
        P[i] = o;
    }
}

// ---------------- pack + transpose BOTH weights in one launch ----------------
__global__ void pack_wt_both(const float* __restrict__ W1, const float* __restrict__ W2,
                             uint32_t* __restrict__ Bt1, uint32_t* __restrict__ Bt2) {
    const int t1 = IN_F * H1_F;
    const int total = t1 + H1_F * H2_F;
    int stride = gridDim.x * blockDim.x;
    for (int idx = blockIdx.x * blockDim.x + threadIdx.x; idx < total; idx += stride) {
        if (idx < t1) {
            int k = idx / H1_F, n = idx - k * H1_F;
            Bt1[(size_t)n * IN_F + k] = pack_hl(W1[idx]);
        } else {
            int i2 = idx - t1;
            int k = i2 / H2_F, n = i2 - k * H2_F;
            Bt2[(size_t)n * H1_F + k] = pack_hl(W2[i2]);
        }
    }
}

// ---------------- split-bf16 MFMA GEMM (128x128 tile, BK=32, 4 waves) ----------------
// D = Am@Bm + Am@Br + Ar@Bm  (fp32-class accuracy). Writes bf16.
__device__ inline void split_frag(const u32x4& lo, const u32x4& hi,
                                  short8& mainf, short8& resf) {
    u32x4 mm, rr;
    mm.x = __builtin_amdgcn_perm(lo.y, lo.x, 0x05040100u);
    mm.y = __builtin_amdgcn_perm(lo.w, lo.z, 0x05040100u);
    mm.z = __builtin_amdgcn_perm(hi.y, hi.x, 0x05040100u);
    mm.w = __builtin_amdgcn_perm(hi.w, hi.z, 0x05040100u);
    rr.x = __builtin_amdgcn_perm(lo.y, lo.x, 0x07060302u);
    rr.y = __builtin_amdgcn_perm(lo.w, lo.z, 0x07060302u);
    rr.z = __builtin_amdgcn_perm(hi.y, hi.x, 0x07060302u);
    rr.w = __builtin_amdgcn_perm(hi.w, hi.z, 0x07060302u);
    mainf = __builtin_bit_cast(short8, mm);
    resf  = __builtin_bit_cast(short8, rr);
}

template <bool ROWSCALE>
__global__ __launch_bounds__(256, 1) void gemm_split(
        const uint32_t* __restrict__ Apk, const uint32_t* __restrict__ Btpk,
        __hip_bfloat16* __restrict__ Cout, const int* __restrict__ rowcnt,
        int M, int Nout, int K) {
    __shared__ uint32_t Al[128 * 32];
    __shared__ uint32_t Bl[128 * 32];
    const int tid = threadIdx.x;
    const int lane = tid & 63, wid = tid >> 6;
    const int wm = wid >> 1, wn = wid & 1;
    const int l15 = lane & 15, lhi = lane >> 4;
    const int brow = blockIdx.x * 128, bcol = blockIdx.y * 128;

    f32x4 acc[4][4];
#pragma unroll
    for (int m = 0; m < 4; ++m)
#pragma unroll
        for (int n = 0; n < 4; ++n) acc[m][n] = f32x4{0.f, 0.f, 0.f, 0.f};

    for (int k0 = 0; k0 < K; k0 += 32) {
#pragma unroll
        for (int i = 0; i < 4; ++i) {
            int chunk = i * 256 + tid;
            int r = chunk >> 3, c16 = chunk & 7;
            int c16s = c16 ^ (r & 7);
            gld_lds16(Apk + (size_t)(brow + r) * K + k0 + c16s * 4, Al + chunk * 4);
            gld_lds16(Btpk + (size_t)(bcol + r) * K + k0 + c16s * 4, Bl + chunk * 4);
        }
        __syncthreads();

        u32x4 apk[4][2], bpk[4][2];
#pragma unroll
        for (int m = 0; m < 4; ++m) {
            int row = wm * 64 + m * 16 + l15;
            const uint32_t* base = Al + row * 32;
            int rs = row & 7;
            apk[m][0] = *(const u32x4*)(base + (((lhi << 1) ^ rs) << 2));
            apk[m][1] = *(const u32x4*)(base + ((((lhi << 1) | 1) ^ rs) << 2));
        }
#pragma unroll
        for (int n = 0; n < 4; ++n) {
            int col = wn * 64 + n * 16 + l15;
            const uint32_t* base = Bl + col * 32;
            int rs = col & 7;
            bpk[n][0] = *(const u32x4*)(base + (((lhi << 1) ^ rs) << 2));
            bpk[n][1] = *(const u32x4*)(base + ((((lhi << 1) | 1) ^ rs) << 2));
        }
        short8 am[4], ar[4], bm[4], br[4];
#pragma unroll
        for (int m = 0; m < 4; ++m) split_frag(apk[m][0], apk[m][1], am[m], ar[m]);
#pragma unroll
        for (int n = 0; n < 4; ++n) split_frag(bpk[n][0], bpk[n][1], bm[n], br[n]);

#pragma unroll
        for (int m = 0; m < 4; ++m)
#pragma unroll
            for (int n = 0; n < 4; ++n) {
                f32x4 c = acc[m][n];
                c = __builtin_amdgcn_mfma_f32_16x16x32_bf16(ar[m], bm[n], c, 0, 0, 0);
                c = __builtin_amdgcn_mfma_f32_16x16x32_bf16(am[m], br[n], c, 0, 0, 0);
                c = __builtin_amdgcn_mfma_f32_16x16x32_bf16(am[m], bm[n], c, 0, 0, 0);
                acc[m][n] = c;
            }
        __syncthreads();
    }

    // epilogue: C/D layout col = lane&15, row = (lane>>4)*4 + j
#pragma unroll
    for (int m = 0; m < 4; ++m) {
        int rbase = brow + wm * 64 + m * 16 + lhi * 4;
        float scl[4];
#pragma unroll
        for (int j = 0; j < 4; ++j) {
            scl[j] = 1.f;
            if (ROWSCALE && rbase + j < M)
                scl[j] = rsqrtf(fmaxf((float)rowcnt[rbase + j], 1.f));
        }
#pragma unroll
        for (int n = 0; n < 4; ++n) {
            int col = bcol + wn * 64 + n * 16 + l15;
#pragma unroll
            for (int j = 0; j < 4; ++j) {
                int row = rbase + j;
                if (row < M)
                    Cout[(size_t)row * Nout + col] = __float2bfloat16(acc[m][n][j] * scl[j]);
            }
        }
    }
}

// ---------------- SpMM1: 8 edges in flight, uint4 gathers, 4 XCD-affine slices ----------------
// wave = one (node, slice); lane: el = lane>>3 (edge slot), fo = lane&7 (16B feat chunk)
__global__ void spmm1_g8(const uint4* __restrict__ h4,   // rows of 32 uint4 (256 bf16 feats)
                         const unsigned long long* __restrict__ s_pk,
                         const int* __restrict__ row_start, const int* __restrict__ in_cnt,
                         const float* __restrict__ b1, uint32_t* __restrict__ h1pk, int N) {
    int bx = blockIdx.x;
    int slice = bx & 3;              // XCD x serves slice x&3 only
    int grp = bx >> 2;
    int wid = threadIdx.x >> 6, lane = threadIdx.x & 63;
    int node = grp * 4 + wid;
    if (node >= N) return;
    int start = row_start[node], cnt = in_cnt[node];
    int el = lane >> 3, fo = lane & 7;
    const uint4* hb = h4 + slice * 8 + fo;
    float acc[8] = {};
    for (int j = el; j < cnt; j += 8) {
        unsigned long long m = s_pk[start + j];
        int s = (int)(unsigned)m;
        float w = __builtin_bit_cast(float, (unsigned)(m >> 32));
        uint4 v = hb[(size_t)s * 32];
        acc[0] = fmaf(w, bf_lo(v.x), acc[0]); acc[1] = fmaf(w, bf_hi(v.x), acc[1]);
        acc[2] = fmaf(w, bf_lo(v.y), acc[2]); acc[3] = fmaf(w, bf_hi(v.y), acc[3]);
        acc[4] = fmaf(w, bf_lo(v.z), acc[4]); acc[5] = fmaf(w, bf_hi(v.z), acc[5]);
        acc[6] = fmaf(w, bf_lo(v.w), acc[6]); acc[7] = fmaf(w, bf_hi(v.w), acc[7]);
    }
#pragma unroll
    for (int d = 8; d < 64; d <<= 1)
#pragma unroll
        for (int k = 0; k < 8; ++k) acc[k] += __shfl_xor(acc[k], d);
    if (el == 0) {
        int fi = slice * 64 + fo * 8;
        u32x4 o0, o1;
        o0.x = pack_hl(fmaxf(acc[0] + b1[fi + 0], 0.f));
        o0.y = pack_hl(fmaxf(acc[1] + b1[fi + 1], 0.f));
        o0.z = pack_hl(fmaxf(acc[2] + b1[fi + 2], 0.f));
        o0.w = pack_hl(fmaxf(acc[3] + b1[fi + 3], 0.f));
        o1.x = pack_hl(fmaxf(acc[4] + b1[fi + 4], 0.f));
        o1.y = pack_hl(fmaxf(acc[5] + b1[fi + 5], 0.f));
        o1.z = pack_hl(fmaxf(acc[6] + b1[fi + 6], 0.f));
        o1.w = pack_hl(fmaxf(acc[7] + b1[fi + 7], 0.f));
        uint32_t* dp = h1pk + (size_t)node * H1_F + fi;
        *(u32x4*)dp = o0;
        *(u32x4*)(dp + 4) = o1;
    }
}

// ---------------- SpMM2: 8 edges in flight, uint4 gathers, 2 XCD-affine slices ----------------
__global__ void spmm2_g8(const uint4* __restrict__ h4,   // rows of 16 uint4 (128 bf16 feats)
                         const unsigned long long* __restrict__ s_pk,
                         const int* __restrict__ row_start, const int* __restrict__ in_cnt,
                         const float* __restrict__ b2, float* __restrict__ out, int N) {
    int bx = blockIdx.x;
    int slice = bx & 1;
    int grp = bx >> 1;
    int wid = threadIdx.x >> 6, lane = threadIdx.x & 63;
    int node = grp * 4 + wid;
    if (node >= N) return;
    int start = row_start[node], cnt = in_cnt[node];
    int el = lane >> 3, fo = lane & 7;
    const uint4* hb = h4 + slice * 8 + fo;
    float acc[8] = {};
    for (int j = el; j < cnt; j += 8) {
        unsigned long long m = s_pk[start + j];
        int s = (int)(unsigned)m;
        uint4 v = hb[(size_t)s * 16];
        acc[0] += bf_lo(v.x); acc[1] += bf_hi(v.x);
        acc[2] += bf_lo(v.y); acc[3] += bf_hi(v.y);
        acc[4] += bf_lo(v.z); acc[5] += bf_hi(v.z);
        acc[6] += bf_lo(v.w); acc[7] += bf_hi(v.w);
    }
#pragma unroll
    for (int d = 8; d < 64; d <<= 1)
#pragma unroll
        for (int k = 0; k < 8; ++k) acc[k] += __shfl_xor(acc[k], d);
    if (el == 0) {
        float rin = rsqrtf(fmaxf((float)cnt, 1.f));
        int fi = slice * 64 + fo * 8;
        f32x4 r0, r1;
        r0.x = acc[0] * rin + b2[fi + 0];
        r0.y = acc[1] * rin + b2[fi + 1];
        r0.z = acc[2] * rin + b2[fi + 2];
        r0.w = acc[3] * rin + b2[fi + 3];
        r1.x = acc[4] * rin + b2[fi + 4];
        r1.y = acc[5] * rin + b2[fi + 5];
        r1.z = acc[6] * rin + b2[fi + 6];
        r1.w = acc[7] * rin + b2[fi + 7];
        float* dp = out + (size_t)node * H2_F + fi;
        *(f32x4*)dp = r0;
        *(f32x4*)(dp + 4) = r1;
    }
}

extern "C" void kernel_launch(void* const* d_in, const int* in_sizes, int n_in,
                              void* d_out, int out_size, void* d_ws, size_t ws_size,
                              hipStream_t stream) {
    const float* features = (const float*)d_in[0];
    const float* edge_w   = (const float*)d_in[1];
    const int*   src      = (const int*)d_in[2];
    const int*   dst      = (const int*)d_in[3];
    const float* W1       = (const float*)d_in[4];
    const float* b1       = (const float*)d_in[5];
    const float* W2       = (const float*)d_in[6];
    const float* b2       = (const float*)d_in[7];
    float* out = (float*)d_out;

    const int N = in_sizes[0] / IN_F;   // 20000
    const int E = in_sizes[1];          // 640000

    char* base = (char*)d_ws;
    size_t off = 0;
    auto alloc = [&](size_t bytes) {
        char* p = base + off;
        off = (off + bytes + 255) & ~(size_t)255;
        return p;
    };
    unsigned long long* out_pk4 = (unsigned long long*)alloc((size_t)N * 4 * 8);
    int*   in_cnt4   = (int*)  alloc((size_t)N * 4 * 4);
    int*   cbase4    = (int*)  alloc((size_t)N * 4 * 4);
    int*   out_cnt   = (int*)  alloc((size_t)N * 4);
    float* out_rs    = (float*)alloc((size_t)N * 4);
    int*   in_cnt    = (int*)  alloc((size_t)N * 4);
    int*   row_start = (int*)  alloc((size_t)N * 4);
    int*   slot      = (int*)  alloc((size_t)E * 4);
    unsigned long long* s_meta = (unsigned long long*)alloc((size_t)E * 8);
    unsigned long long* s_pk   = (unsigned long long*)alloc((size_t)E * 8);
    uint32_t* Bt1    = (uint32_t*)alloc((size_t)H1_F * IN_F * 4);
    uint32_t* Bt2    = (uint32_t*)alloc((size_t)H2_F * H1_F * 4);
    __hip_bfloat16* h_bf = (__hip_bfloat16*)alloc((size_t)MPAD * H1_F * 2);
    uint32_t* Apk    = (uint32_t*)alloc((size_t)MPAD * IN_F * 4);
    // overlays inside Apk (Apk dead after GEMM1; stream order makes this safe)
    uint32_t* h1pk = Apk;                               // [MPAD][256] u32
    uint32_t* h2b  = Apk + (size_t)MPAD * H1_F;         // [MPAD][64] u32 of bf16x2
    (void)ws_size;

    hipMemsetAsync(out_pk4, 0, (size_t)N * 4 * 8, stream);
    hipMemsetAsync(in_cnt4, 0, (size_t)N * 4 * 4, stream);

    // ---- CSR build + norms ----
    count_kernel<<<1024, 256, 0, stream>>>(edge_w, src, dst, out_pk4, in_cnt4, slot, E);
    scan_kernel<<<1, 1024, 0, stream>>>(out_pk4, in_cnt4, out_cnt, out_rs,
                                        cbase4, in_cnt, row_start, N);
    scatter2_kernel<<<1024, 256, 0, stream>>>(edge_w, src, dst, row_start, cbase4,
                                              slot, s_meta, E);
    in_finalize<<<N, 64, 0, stream>>>(s_meta, out_rs, row_start, in_cnt, s_pk, N);

    // ---- operand packing ----
    pack_rows<<<2048, 256, 0, stream>>>((const float4*)features, (u32x4*)Apk, N * IN_F / 4);
    pack_wt_both<<<320, 256, 0, stream>>>(W1, W2, Bt1, Bt2);

    // ---- layer 1 ----
    dim3 g1(MPAD / 128, H1_F / 128);
    gemm_split<false><<<g1, 256, 0, stream>>>(Apk, Bt1, h_bf, nullptr, N, H1_F, IN_F);
    int grp = (N + 3) / 4;
    spmm1_g8<<<grp * 4, 256, 0, stream>>>((const uint4*)h_bf, s_pk,
                                          row_start, in_cnt, b1, h1pk, N);
    // ---- layer 2 ----
    dim3 g2(MPAD / 128, H2_F / 128);
    gemm_split<true><<<g2, 256, 0, stream>>>(h1pk, Bt2, (__hip_bfloat16*)h2b, out_cnt,
                                             N, H2_F, H1_F);
    spmm2_g8<<<grp * 2, 256, 0, stream>>>((const uint4*)h2b, s_pk,
                                          row_start, in_cnt, b2, out, N);
}

// Round 5
// 248.180 us; speedup vs baseline: 1.3570x; 1.3570x over previous
//
#include <hip/hip_runtime.h>
#include <hip/hip_bf16.h>
#include <stdint.h>

#define IN_F 512
#define H1_F 256
#define H2_F 128
#define MPAD 20096   // 157*128, padded row count for 128-row GEMM tiles

typedef __attribute__((ext_vector_type(8))) short short8;   // 8 bf16 (4 VGPRs)
typedef __attribute__((ext_vector_type(4))) float f32x4;
typedef __attribute__((ext_vector_type(4))) uint32_t u32x4;

// ---- fp32 -> (bf16 main | bf16 residual) packed in one u32 ----
__device__ inline uint32_t pack_hl(float x) {
    __hip_bfloat16 m = __float2bfloat16(x);
    float mf = __bfloat162float(m);
    __hip_bfloat16 r = __float2bfloat16(x - mf);
    return (uint32_t)__builtin_bit_cast(unsigned short, m) |
           ((uint32_t)__builtin_bit_cast(unsigned short, r) << 16);
}

__device__ inline float bf_lo(uint32_t v) { return __builtin_bit_cast(float, v << 16); }
__device__ inline float bf_hi(uint32_t v) { return __builtin_bit_cast(float, v & 0xffff0000u); }

__device__ inline void gld_lds16(const uint32_t* g, uint32_t* l) {
    __builtin_amdgcn_global_load_lds((const __attribute__((address_space(1))) uint32_t*)g,
                                     (__attribute__((address_space(3))) uint32_t*)l,
                                     16, 0, 0);
}

// ---------------- pass 1: privatized (x4) atomics ----------------
// out_pk4 bits [39:0] = sum w*2^24 fixed point; bits [63:40] = count
__global__ void count_kernel(const float* __restrict__ ew, const int* __restrict__ src,
                             const int* __restrict__ dst,
                             unsigned long long* __restrict__ out_pk4,
                             int* __restrict__ in_cnt4, int* __restrict__ slot, int E) {
    int stride = gridDim.x * blockDim.x;
    int c = threadIdx.x & 3;
    for (int e = blockIdx.x * blockDim.x + threadIdx.x; e < E; e += stride) {
        float w = ew[e];
        unsigned long long v = (1ULL << 40) |
            (unsigned long long)__float2uint_rn(w * 16777216.0f);
        atomicAdd(&out_pk4[(size_t)src[e] * 4 + c], v);
        int intra = atomicAdd(&in_cnt4[(size_t)dst[e] * 4 + c], 1);
        slot[e] = (c << 28) | intra;
    }
}

// ---------------- grid-parallel per-node unpack (was wrongly in the scan) ----------------
__global__ void unpack_kernel(const unsigned long long* __restrict__ out_pk4,
                              const int* __restrict__ in_cnt4,
                              int* __restrict__ out_cnt, float* __restrict__ out_rs,
                              int* __restrict__ cbase4, int* __restrict__ in_cnt, int n) {
    const unsigned long long M40 = (1ULL << 40) - 1;
    int i = blockIdx.x * blockDim.x + threadIdx.x;
    if (i >= n) return;
    unsigned long long lo = 0; int oc = 0;
#pragma unroll
    for (int c = 0; c < 4; ++c) {
        unsigned long long o = out_pk4[(size_t)i * 4 + c];
        lo += o & M40;
        oc += (int)(o >> 40);
    }
    out_cnt[i] = oc;
    out_rs[i] = (oc > 0) ? rsqrtf((float)lo * (1.0f / 16777216.0f)) : 0.f;
    int c0 = in_cnt4[(size_t)i * 4 + 0], c1 = in_cnt4[(size_t)i * 4 + 1];
    int c2 = in_cnt4[(size_t)i * 4 + 2], c3 = in_cnt4[(size_t)i * 4 + 3];
    cbase4[(size_t)i * 4 + 0] = 0;
    cbase4[(size_t)i * 4 + 1] = c0;
    cbase4[(size_t)i * 4 + 2] = c0 + c1;
    cbase4[(size_t)i * 4 + 3] = c0 + c1 + c2;
    in_cnt[i] = c0 + c1 + c2 + c3;
}

// ---------------- prefix-sum ONLY: coalesced tiles, wave shfl scans ----------------
__global__ void scan_kernel(const int* __restrict__ cnt, int* __restrict__ row_start, int n) {
    __shared__ int wsum[16];
    __shared__ int carry_s;
    int tid = threadIdx.x;
    int wid = tid >> 6, lane = tid & 63;
    if (tid == 0) carry_s = 0;
    __syncthreads();
    for (int base = 0; base < n; base += 1024) {
        int i = base + tid;
        int v = (i < n) ? cnt[i] : 0;
        int x = v;
#pragma unroll
        for (int d = 1; d < 64; d <<= 1) {
            int t = __shfl_up(x, d);
            if (lane >= d) x += t;
        }
        if (lane == 63) wsum[wid] = x;
        __syncthreads();
        if (wid == 0) {
            int p = (lane < 16) ? wsum[lane] : 0;
#pragma unroll
            for (int d = 1; d < 16; d <<= 1) {
                int t = __shfl_up(p, d);
                if (lane >= d) p += t;
            }
            if (lane < 16) wsum[lane] = p;   // inclusive over wave partials
        }
        __syncthreads();
        int woff = (wid > 0) ? wsum[wid - 1] : 0;
        if (i < n) row_start[i] = carry_s + woff + x - v;
        int total = wsum[15];
        __syncthreads();
        if (tid == 0) carry_s += total;
        __syncthreads();
    }
}

// ---------------- pass 2: atomic-free bucket write (src|ew packed u64) ----------------
__global__ void scatter2_kernel(const float* __restrict__ ew, const int* __restrict__ src,
                                const int* __restrict__ dst,
                                const int* __restrict__ row_start, const int* __restrict__ cbase4,
                                const int* __restrict__ slot,
                                unsigned long long* __restrict__ s_pk, int E) {
    int stride = gridDim.x * blockDim.x;
    for (int e = blockIdx.x * blockDim.x + threadIdx.x; e < E; e += stride) {
        int d = dst[e];
        int sl = slot[e];
        int p = row_start[d] + cbase4[(size_t)d * 4 + (sl >> 28)] + (sl & 0x0FFFFFFF);
        unsigned long long m = (unsigned long long)(unsigned)src[e] |
            ((unsigned long long)__builtin_bit_cast(unsigned, ew[e]) << 32);
        s_pk[p] = m;
    }
}

// ---------------- per-node: in_wsum segment sum + rewrite s_pk = (src | nw<<32) in place ----------------
__global__ void in_finalize(const float* __restrict__ out_rs,
                            const int* __restrict__ row_start, const int* __restrict__ in_cnt,
                            unsigned long long* __restrict__ s_pk, int N) {
    int node = blockIdx.x;
    int lane = threadIdx.x;
    int start = row_start[node], cnt = in_cnt[node];
    float sum = 0.f;
    for (int j = lane; j < cnt; j += 64)
        sum += __builtin_bit_cast(float, (unsigned)(s_pk[start + j] >> 32));
    for (int d = 1; d < 64; d <<= 1) sum += __shfl_xor(sum, d);
    float rin = (cnt > 0) ? rsqrtf(sum) : 0.f;
    for (int j = lane; j < cnt; j += 64) {
        unsigned long long m = s_pk[start + j];
        int s = (int)(unsigned)m;
        float w = __builtin_bit_cast(float, (unsigned)(m >> 32));
        float nw = w * out_rs[s] * rin;
        s_pk[start + j] = (unsigned long long)(unsigned)s |
                          ((unsigned long long)__builtin_bit_cast(unsigned, nw) << 32);
    }
}

// ---------------- pack fp32 matrix -> hi/lo bf16 u32 (row-major) ----------------
__global__ void pack_rows(const float4* __restrict__ X, u32x4* __restrict__ P, int n4) {
    int stride = gridDim.x * blockDim.x;
    for (int i = blockIdx.x * blockDim.x + threadIdx.x; i < n4; i += stride) {
        float4 x = X[i];
        u32x4 o;
        o.x = pack_hl(x.x); o.y = pack_hl(x.y);
        o.z = pack_hl(x.z); o.w = pack_hl(x.w);
        P[i] = o;
    }
}

// ---------------- pack + transpose BOTH weights in one launch ----------------
__global__ void pack_wt_both(const float* __restrict__ W1, const float* __restrict__ W2,
                             uint32_t* __restrict__ Bt1, uint32_t* __restrict__ Bt2) {
    const int t1 = IN_F * H1_F;
    const int total = t1 + H1_F * H2_F;
    int stride = gridDim.x * blockDim.x;
    for (int idx = blockIdx.x * blockDim.x + threadIdx.x; idx < total; idx += stride) {
        if (idx < t1) {
            int k = idx / H1_F, n = idx - k * H1_F;
            Bt1[(size_t)n * IN_F + k] = pack_hl(W1[idx]);
        } else {
            int i2 = idx - t1;
            int k = i2 / H2_F, n = i2 - k * H2_F;
            Bt2[(size_t)n * H1_F + k] = pack_hl(W2[i2]);
        }
    }
}

// ---------------- split-bf16 MFMA GEMM (128x128 tile, BK=32, 4 waves) ----------------
// D = Am@Bm + Am@Br + Ar@Bm  (fp32-class accuracy). Writes bf16.
__device__ inline void split_frag(const u32x4& lo, const u32x4& hi,
                                  short8& mainf, short8& resf) {
    u32x4 mm, rr;
    mm.x = __builtin_amdgcn_perm(lo.y, lo.x, 0x05040100u);
    mm.y = __builtin_amdgcn_perm(lo.w, lo.z, 0x05040100u);
    mm.z = __builtin_amdgcn_perm(hi.y, hi.x, 0x05040100u);
    mm.w = __builtin_amdgcn_perm(hi.w, hi.z, 0x05040100u);
    rr.x = __builtin_amdgcn_perm(lo.y, lo.x, 0x07060302u);
    rr.y = __builtin_amdgcn_perm(lo.w, lo.z, 0x07060302u);
    rr.z = __builtin_amdgcn_perm(hi.y, hi.x, 0x07060302u);
    rr.w = __builtin_amdgcn_perm(hi.w, hi.z, 0x07060302u);
    mainf = __builtin_bit_cast(short8, mm);
    resf  = __builtin_bit_cast(short8, rr);
}

template <bool ROWSCALE>
__global__ __launch_bounds__(256, 1) void gemm_split(
        const uint32_t* __restrict__ Apk, const uint32_t* __restrict__ Btpk,
        __hip_bfloat16* __restrict__ Cout, const int* __restrict__ rowcnt,
        int M, int Nout, int K) {
    __shared__ uint32_t Al[128 * 32];
    __shared__ uint32_t Bl[128 * 32];
    const int tid = threadIdx.x;
    const int lane = tid & 63, wid = tid >> 6;
    const int wm = wid >> 1, wn = wid & 1;
    const int l15 = lane & 15, lhi = lane >> 4;
    const int brow = blockIdx.x * 128, bcol = blockIdx.y * 128;

    f32x4 acc[4][4];
#pragma unroll
    for (int m = 0; m < 4; ++m)
#pragma unroll
        for (int n = 0; n < 4; ++n) acc[m][n] = f32x4{0.f, 0.f, 0.f, 0.f};

    for (int k0 = 0; k0 < K; k0 += 32) {
#pragma unroll
        for (int i = 0; i < 4; ++i) {
            int chunk = i * 256 + tid;
            int r = chunk >> 3, c16 = chunk & 7;
            int c16s = c16 ^ (r & 7);
            gld_lds16(Apk + (size_t)(brow + r) * K + k0 + c16s * 4, Al + chunk * 4);
            gld_lds16(Btpk + (size_t)(bcol + r) * K + k0 + c16s * 4, Bl + chunk * 4);
        }
        __syncthreads();

        u32x4 apk[4][2], bpk[4][2];
#pragma unroll
        for (int m = 0; m < 4; ++m) {
            int row = wm * 64 + m * 16 + l15;
            const uint32_t* base = Al + row * 32;
            int rs = row & 7;
            apk[m][0] = *(const u32x4*)(base + (((lhi << 1) ^ rs) << 2));
            apk[m][1] = *(const u32x4*)(base + ((((lhi << 1) | 1) ^ rs) << 2));
        }
#pragma unroll
        for (int n = 0; n < 4; ++n) {
            int col = wn * 64 + n * 16 + l15;
            const uint32_t* base = Bl + col * 32;
            int rs = col & 7;
            bpk[n][0] = *(const u32x4*)(base + (((lhi << 1) ^ rs) << 2));
            bpk[n][1] = *(const u32x4*)(base + ((((lhi << 1) | 1) ^ rs) << 2));
        }
        short8 am[4], ar[4], bm[4], br[4];
#pragma unroll
        for (int m = 0; m < 4; ++m) split_frag(apk[m][0], apk[m][1], am[m], ar[m]);
#pragma unroll
        for (int n = 0; n < 4; ++n) split_frag(bpk[n][0], bpk[n][1], bm[n], br[n]);

#pragma unroll
        for (int m = 0; m < 4; ++m)
#pragma unroll
            for (int n = 0; n < 4; ++n) {
                f32x4 c = acc[m][n];
                c = __builtin_amdgcn_mfma_f32_16x16x32_bf16(ar[m], bm[n], c, 0, 0, 0);
                c = __builtin_amdgcn_mfma_f32_16x16x32_bf16(am[m], br[n], c, 0, 0, 0);
                c = __builtin_amdgcn_mfma_f32_16x16x32_bf16(am[m], bm[n], c, 0, 0, 0);
                acc[m][n] = c;
            }
        __syncthreads();
    }

    // epilogue: C/D layout col = lane&15, row = (lane>>4)*4 + j
#pragma unroll
    for (int m = 0; m < 4; ++m) {
        int rbase = brow + wm * 64 + m * 16 + lhi * 4;
        float scl[4];
#pragma unroll
        for (int j = 0; j < 4; ++j) {
            scl[j] = 1.f;
            if (ROWSCALE && rbase + j < M)
                scl[j] = rsqrtf(fmaxf((float)rowcnt[rbase + j], 1.f));
        }
#pragma unroll
        for (int n = 0; n < 4; ++n) {
            int col = bcol + wn * 64 + n * 16 + l15;
#pragma unroll
            for (int j = 0; j < 4; ++j) {
                int row = rbase + j;
                if (row < M)
                    Cout[(size_t)row * Nout + col] = __float2bfloat16(acc[m][n][j] * scl[j]);
            }
        }
    }
}

// ---------------- SpMM1: 8 edges in flight, uint4 gathers, 4 XCD-affine slices ----------------
// wave = one (node, slice); lane: el = lane>>3 (edge slot), fo = lane&7 (16B feat chunk)
__global__ void spmm1_g8(const uint4* __restrict__ h4,   // rows of 32 uint4 (256 bf16 feats)
                         const unsigned long long* __restrict__ s_pk,
                         const int* __restrict__ row_start, const int* __restrict__ in_cnt,
                         const float* __restrict__ b1, uint32_t* __restrict__ h1pk, int N) {
    int bx = blockIdx.x;
    int slice = bx & 3;              // XCD x serves slice x&3 only
    int grp = bx >> 2;
    int wid = threadIdx.x >> 6, lane = threadIdx.x & 63;
    int node = grp * 4 + wid;
    if (node >= N) return;
    int start = row_start[node], cnt = in_cnt[node];
    int el = lane >> 3, fo = lane & 7;
    const uint4* hb = h4 + slice * 8 + fo;
    float acc[8] = {};
    for (int j = el; j < cnt; j += 8) {
        unsigned long long m = s_pk[start + j];
        int s = (int)(unsigned)m;
        float w = __builtin_bit_cast(float, (unsigned)(m >> 32));
        uint4 v = hb[(size_t)s * 32];
        acc[0] = fmaf(w, bf_lo(v.x), acc[0]); acc[1] = fmaf(w, bf_hi(v.x), acc[1]);
        acc[2] = fmaf(w, bf_lo(v.y), acc[2]); acc[3] = fmaf(w, bf_hi(v.y), acc[3]);
        acc[4] = fmaf(w, bf_lo(v.z), acc[4]); acc[5] = fmaf(w, bf_hi(v.z), acc[5]);
        acc[6] = fmaf(w, bf_lo(v.w), acc[6]); acc[7] = fmaf(w, bf_hi(v.w), acc[7]);
    }
#pragma unroll
    for (int d = 8; d < 64; d <<= 1)
#pragma unroll
        for (int k = 0; k < 8; ++k) acc[k] += __shfl_xor(acc[k], d);
    if (el == 0) {
        int fi = slice * 64 + fo * 8;
        u32x4 o0, o1;
        o0.x = pack_hl(fmaxf(acc[0] + b1[fi + 0], 0.f));
        o0.y = pack_hl(fmaxf(acc[1] + b1[fi + 1], 0.f));
        o0.z = pack_hl(fmaxf(acc[2] + b1[fi + 2], 0.f));
        o0.w = pack_hl(fmaxf(acc[3] + b1[fi + 3], 0.f));
        o1.x = pack_hl(fmaxf(acc[4] + b1[fi + 4], 0.f));
        o1.y = pack_hl(fmaxf(acc[5] + b1[fi + 5], 0.f));
        o1.z = pack_hl(fmaxf(acc[6] + b1[fi + 6], 0.f));
        o1.w = pack_hl(fmaxf(acc[7] + b1[fi + 7], 0.f));
        uint32_t* dp = h1pk + (size_t)node * H1_F + fi;
        *(u32x4*)dp = o0;
        *(u32x4*)(dp + 4) = o1;
    }
}

// ---------------- SpMM2: 8 edges in flight, uint4 gathers, 2 XCD-affine slices ----------------
__global__ void spmm2_g8(const uint4* __restrict__ h4,   // rows of 16 uint4 (128 bf16 feats)
                         const unsigned long long* __restrict__ s_pk,
                         const int* __restrict__ row_start, const int* __restrict__ in_cnt,
                         const float* __restrict__ b2, float* __restrict__ out, int N) {
    int bx = blockIdx.x;
    int slice = bx & 1;
    int grp = bx >> 1;
    int wid = threadIdx.x >> 6, lane = threadIdx.x & 63;
    int node = grp * 4 + wid;
    if (node >= N) return;
    int start = row_start[node], cnt = in_cnt[node];
    int el = lane >> 3, fo = lane & 7;
    const uint4* hb = h4 + slice * 8 + fo;
    float acc[8] = {};
    for (int j = el; j < cnt; j += 8) {
        unsigned long long m = s_pk[start + j];
        int s = (int)(unsigned)m;
        uint4 v = hb[(size_t)s * 16];
        acc[0] += bf_lo(v.x); acc[1] += bf_hi(v.x);
        acc[2] += bf_lo(v.y); acc[3] += bf_hi(v.y);
        acc[4] += bf_lo(v.z); acc[5] += bf_hi(v.z);
        acc[6] += bf_lo(v.w); acc[7] += bf_hi(v.w);
    }
#pragma unroll
    for (int d = 8; d < 64; d <<= 1)
#pragma unroll
        for (int k = 0; k < 8; ++k) acc[k] += __shfl_xor(acc[k], d);
    if (el == 0) {
        float rin = rsqrtf(fmaxf((float)cnt, 1.f));
        int fi = slice * 64 + fo * 8;
        f32x4 r0, r1;
        r0.x = acc[0] * rin + b2[fi + 0];
        r0.y = acc[1] * rin + b2[fi + 1];
        r0.z = acc[2] * rin + b2[fi + 2];
        r0.w = acc[3] * rin + b2[fi + 3];
        r1.x = acc[4] * rin + b2[fi + 4];
        r1.y = acc[5] * rin + b2[fi + 5];
        r1.z = acc[6] * rin + b2[fi + 6];
        r1.w = acc[7] * rin + b2[fi + 7];
        float* dp = out + (size_t)node * H2_F + fi;
        *(f32x4*)dp = r0;
        *(f32x4*)(dp + 4) = r1;
    }
}

extern "C" void kernel_launch(void* const* d_in, const int* in_sizes, int n_in,
                              void* d_out, int out_size, void* d_ws, size_t ws_size,
                              hipStream_t stream) {
    const float* features = (const float*)d_in[0];
    const float* edge_w   = (const float*)d_in[1];
    const int*   src      = (const int*)d_in[2];
    const int*   dst      = (const int*)d_in[3];
    const float* W1       = (const float*)d_in[4];
    const float* b1       = (const float*)d_in[5];
    const float* W2       = (const float*)d_in[6];
    const float* b2       = (const float*)d_in[7];
    float* out = (float*)d_out;

    const int N = in_sizes[0] / IN_F;   // 20000
    const int E = in_sizes[1];          // 640000

    char* base = (char*)d_ws;
    size_t off = 0;
    auto alloc = [&](size_t bytes) {
        char* p = base + off;
        off = (off + bytes + 255) & ~(size_t)255;
        return p;
    };
    unsigned long long* out_pk4 = (unsigned long long*)alloc((size_t)N * 4 * 8);
    int*   in_cnt4   = (int*)  alloc((size_t)N * 4 * 4);
    int*   cbase4    = (int*)  alloc((size_t)N * 4 * 4);
    int*   out_cnt   = (int*)  alloc((size_t)N * 4);
    float* out_rs    = (float*)alloc((size_t)N * 4);
    int*   in_cnt    = (int*)  alloc((size_t)N * 4);
    int*   row_start = (int*)  alloc((size_t)N * 4);
    int*   slot      = (int*)  alloc((size_t)E * 4);
    unsigned long long* s_pk = (unsigned long long*)alloc((size_t)E * 8);
    uint32_t* Bt1    = (uint32_t*)alloc((size_t)H1_F * IN_F * 4);
    uint32_t* Bt2    = (uint32_t*)alloc((size_t)H2_F * H1_F * 4);
    __hip_bfloat16* h_bf = (__hip_bfloat16*)alloc((size_t)MPAD * H1_F * 2);
    uint32_t* Apk    = (uint32_t*)alloc((size_t)MPAD * IN_F * 4);
    // overlays inside Apk (Apk dead after GEMM1; stream order makes this safe)
    uint32_t* h1pk = Apk;                               // [MPAD][256] u32
    uint32_t* h2b  = Apk + (size_t)MPAD * H1_F;         // [MPAD][64] u32 of bf16x2
    (void)ws_size;

    hipMemsetAsync(out_pk4, 0, (size_t)N * 4 * 8, stream);
    hipMemsetAsync(in_cnt4, 0, (size_t)N * 4 * 4, stream);

    // ---- CSR build + norms ----
    count_kernel<<<1024, 256, 0, stream>>>(edge_w, src, dst, out_pk4, in_cnt4, slot, E);
    unpack_kernel<<<(N + 255) / 256, 256, 0, stream>>>(out_pk4, in_cnt4, out_cnt, out_rs,
                                                       cbase4, in_cnt, N);
    scan_kernel<<<1, 1024, 0, stream>>>(in_cnt, row_start, N);
    scatter2_kernel<<<1024, 256, 0, stream>>>(edge_w, src, dst, row_start, cbase4,
                                              slot, s_pk, E);
    in_finalize<<<N, 64, 0, stream>>>(out_rs, row_start, in_cnt, s_pk, N);

    // ---- operand packing ----
    pack_rows<<<2048, 256, 0, stream>>>((const float4*)features, (u32x4*)Apk, N * IN_F / 4);
    pack_wt_both<<<320, 256, 0, stream>>>(W1, W2, Bt1, Bt2);

    // ---- layer 1 ----
    dim3 g1(MPAD / 128, H1_F / 128);
    gemm_split<false><<<g1, 256, 0, stream>>>(Apk, Bt1, h_bf, nullptr, N, H1_F, IN_F);
    int grp = (N + 3) / 4;
    spmm1_g8<<<grp * 4, 256, 0, stream>>>((const uint4*)h_bf, s_pk,
                                          row_start, in_cnt, b1, h1pk, N);
    // ---- layer 2 ----
    dim3 g2(MPAD / 128, H2_F / 128);
    gemm_split<true><<<g2, 256, 0, stream>>>(h1pk, Bt2, (__hip_bfloat16*)h2b, out_cnt,
                                             N, H2_F, H1_F);
    spmm2_g8<<<grp * 2, 256, 0, stream>>>((const uint4*)h2b, s_pk,
                                          row_start, in_cnt, b2, out, N);
}

// Round 6
// 242.122 us; speedup vs baseline: 1.3910x; 1.0250x over previous
//
#include <hip/hip_runtime.h>
#include <hip/hip_bf16.h>
#include <stdint.h>

#define IN_F 512
#define H1_F 256
#define H2_F 128
#define MPAD 20096   // 157*128, padded row count for 128-row GEMM tiles
#define NN   20000
#define NPAIR 10000  // NN/2
#define BH   128     // histogram blocks (chunks)

typedef __attribute__((ext_vector_type(8))) short short8;   // 8 bf16 (4 VGPRs)
typedef __attribute__((ext_vector_type(4))) float f32x4;
typedef __attribute__((ext_vector_type(4))) uint32_t u32x4;

// ---- fp32 -> (bf16 main | bf16 residual) packed in one u32 ----
__device__ inline uint32_t pack_hl(float x) {
    __hip_bfloat16 m = __float2bfloat16(x);
    float mf = __bfloat162float(m);
    __hip_bfloat16 r = __float2bfloat16(x - mf);
    return (uint32_t)__builtin_bit_cast(unsigned short, m) |
           ((uint32_t)__builtin_bit_cast(unsigned short, r) << 16);
}

__device__ inline float bf_lo(uint32_t v) { return __builtin_bit_cast(float, v << 16); }
__device__ inline float bf_hi(uint32_t v) { return __builtin_bit_cast(float, v & 0xffff0000u); }

__device__ inline void gld_lds16(const uint32_t* g, uint32_t* l) {
    __builtin_amdgcn_global_load_lds((const __attribute__((address_space(1))) uint32_t*)g,
                                     (__attribute__((address_space(3))) uint32_t*)l,
                                     16, 0, 0);
}

// ================= CSR build, zero global atomics =================
// Phase A: per-block u16-packed dst histogram -> Hd[b][NPAIR]
// Phase B/C: per-block src count (u16-packed) + fixed-point wsum over 2 node
//            slices -> Pc[sl][b][NPAIR/2], Pw[sl][b][NPAIR]
// All aggregation via LDS atomics (CU-local); all global traffic coalesced.
__global__ __launch_bounds__(256) void build_partials(
        const int* __restrict__ dst, const int* __restrict__ src,
        const float* __restrict__ ew,
        uint32_t* __restrict__ Hd, uint32_t* __restrict__ Pc,
        uint32_t* __restrict__ Pw, int E, int CH) {
    __shared__ uint32_t buf[15000];           // 60 KB union
    uint32_t* h  = buf;                       // [NPAIR] phase A
    uint32_t* cs = buf;                       // [5000]  phase B/C
    uint32_t* ws = buf + 5000;                // [NPAIR] phase B/C
    const int b = blockIdx.x, tid = threadIdx.x;
    const int e0 = b * CH, e1 = min(e0 + CH, E);

    // ---- phase A: dst histogram ----
    for (int i = tid; i < NPAIR; i += 256) h[i] = 0;
    __syncthreads();
    for (int e = e0 + tid; e < e1; e += 256) {
        int d = dst[e];
        atomicAdd(&h[d >> 1], 1u << ((d & 1) * 16));
    }
    __syncthreads();
    for (int i = tid; i < NPAIR; i += 256) Hd[b * NPAIR + i] = h[i];
    __syncthreads();

    // ---- phases B,C: src count + wsum (fixed point 2^16), node slices ----
    for (int sl = 0; sl < 2; ++sl) {
        for (int i = tid; i < 5000; i += 256) cs[i] = 0;
        for (int i = tid; i < NPAIR; i += 256) ws[i] = 0;
        __syncthreads();
        int lo = sl * NPAIR;
        for (int e = e0 + tid; e < e1; e += 256) {
            int s = src[e] - lo;
            if ((unsigned)s < (unsigned)NPAIR) {
                atomicAdd(&cs[s >> 1], 1u << ((s & 1) * 16));
                atomicAdd(&ws[s], (uint32_t)__float2uint_rn(ew[e] * 65536.0f));
            }
        }
        __syncthreads();
        for (int i = tid; i < 5000; i += 256)
            Pc[(size_t)(sl * BH + b) * 5000 + i] = cs[i];
        for (int i = tid; i < NPAIR; i += 256)
            Pw[(size_t)(sl * BH + b) * NPAIR + i] = ws[i];
        __syncthreads();
    }
}

// thread i owns node pair (2i, 2i+1): per-block exclusive prefixes Od[b][n],
// totals -> in_cnt; reduce src partials -> out_cnt, out_rs.
__global__ void offsets_kernel(const uint32_t* __restrict__ Hd,
                               uint2* __restrict__ Od2, int* __restrict__ in_cnt,
                               const uint32_t* __restrict__ Pc,
                               const uint2* __restrict__ Pw2,
                               int* __restrict__ out_cnt, float* __restrict__ out_rs) {
    int i = blockIdx.x * blockDim.x + threadIdx.x;
    if (i >= NPAIR) return;
    uint32_t c0 = 0, c1 = 0;
    for (int b = 0; b < BH; ++b) {
        uint32_t v = Hd[(size_t)b * NPAIR + i];
        Od2[(size_t)b * NPAIR + i] = make_uint2(c0, c1);
        c0 += v & 0xffffu; c1 += v >> 16;
    }
    *(int2*)&in_cnt[2 * i] = make_int2((int)c0, (int)c1);

    int sl = i / 5000, li = i - sl * 5000;
    uint32_t oc0 = 0, oc1 = 0;
    unsigned long long w0 = 0, w1 = 0;
    for (int b = 0; b < BH; ++b) {
        uint32_t cv = Pc[(size_t)(sl * BH + b) * 5000 + li];
        oc0 += cv & 0xffffu; oc1 += cv >> 16;
        uint2 wv = Pw2[(size_t)(sl * BH + b) * 5000 + li];
        w0 += wv.x; w1 += wv.y;
    }
    *(int2*)&out_cnt[2 * i] = make_int2((int)oc0, (int)oc1);
    float r0 = oc0 ? rsqrtf((float)w0 * (1.0f / 65536.0f)) : 0.f;
    float r1 = oc1 ? rsqrtf((float)w1 * (1.0f / 65536.0f)) : 0.f;
    *(float2*)&out_rs[2 * i] = make_float2(r0, r1);
}

// ---------------- prefix-sum ONLY: coalesced tiles, wave shfl scans ----------------
__global__ void scan_kernel(const int* __restrict__ cnt, int* __restrict__ row_start, int n) {
    __shared__ int wsum[16];
    __shared__ int carry_s;
    int tid = threadIdx.x;
    int wid = tid >> 6, lane = tid & 63;
    if (tid == 0) carry_s = 0;
    __syncthreads();
    for (int base = 0; base < n; base += 1024) {
        int i = base + tid;
        int v = (i < n) ? cnt[i] : 0;
        int x = v;
#pragma unroll
        for (int d = 1; d < 64; d <<= 1) {
            int t = __shfl_up(x, d);
            if (lane >= d) x += t;
        }
        if (lane == 63) wsum[wid] = x;
        __syncthreads();
        if (wid == 0) {
            int p = (lane < 16) ? wsum[lane] : 0;
#pragma unroll
            for (int d = 1; d < 16; d <<= 1) {
                int t = __shfl_up(p, d);
                if (lane >= d) p += t;
            }
            if (lane < 16) wsum[lane] = p;
        }
        __syncthreads();
        int woff = (wid > 0) ? wsum[wid - 1] : 0;
        if (i < n) row_start[i] = carry_s + woff + x - v;
        int total = wsum[15];
        __syncthreads();
        if (tid == 0) carry_s += total;
        __syncthreads();
    }
}

// scatter with LDS-derived ranks (no global atomics): p = row_start + Od + rank
__global__ __launch_bounds__(256) void scatter_dst(
        const int* __restrict__ src, const int* __restrict__ dst,
        const float* __restrict__ ew, const int* __restrict__ row_start,
        const uint32_t* __restrict__ Od, unsigned long long* __restrict__ s_pk,
        int E, int CH) {
    __shared__ uint32_t h[NPAIR];
    const int b = blockIdx.x, tid = threadIdx.x;
    for (int i = tid; i < NPAIR; i += 256) h[i] = 0;
    __syncthreads();
    const int e0 = b * CH, e1 = min(e0 + CH, E);
    const uint32_t* Ob = Od + (size_t)b * NN;
    for (int e = e0 + tid; e < e1; e += 256) {
        int d = dst[e];
        uint32_t old = atomicAdd(&h[d >> 1], 1u << ((d & 1) * 16));
        uint32_t rank = (old >> ((d & 1) * 16)) & 0xffffu;
        int p = row_start[d] + (int)Ob[d] + (int)rank;
        s_pk[p] = (unsigned long long)(unsigned)src[e] |
                  ((unsigned long long)__builtin_bit_cast(unsigned, ew[e]) << 32);
    }
}

// ---------------- per-node: in_wsum segment sum + rewrite s_pk = (src | nw<<32) in place ----------------
__global__ void in_finalize(const float* __restrict__ out_rs,
                            const int* __restrict__ row_start, const int* __restrict__ in_cnt,
                            unsigned long long* __restrict__ s_pk, int N) {
    int node = blockIdx.x;
    int lane = threadIdx.x;
    int start = row_start[node], cnt = in_cnt[node];
    float sum = 0.f;
    for (int j = lane; j < cnt; j += 64)
        sum += __builtin_bit_cast(float, (unsigned)(s_pk[start + j] >> 32));
    for (int d = 1; d < 64; d <<= 1) sum += __shfl_xor(sum, d);
    float rin = (cnt > 0) ? rsqrtf(sum) : 0.f;
    for (int j = lane; j < cnt; j += 64) {
        unsigned long long m = s_pk[start + j];
        int s = (int)(unsigned)m;
        float w = __builtin_bit_cast(float, (unsigned)(m >> 32));
        float nw = w * out_rs[s] * rin;
        s_pk[start + j] = (unsigned long long)(unsigned)s |
                          ((unsigned long long)__builtin_bit_cast(unsigned, nw) << 32);
    }
}

// ---------------- pack fp32 matrix -> hi/lo bf16 u32 (row-major) ----------------
__global__ void pack_rows(const float4* __restrict__ X, u32x4* __restrict__ P, int n4) {
    int stride = gridDim.x * blockDim.x;
    for (int i = blockIdx.x * blockDim.x + threadIdx.x; i < n4; i += stride) {
        float4 x = X[i];
        u32x4 o;
        o.x = pack_hl(x.x); o.y = pack_hl(x.y);
        o.z = pack_hl(x.z); o.w = pack_hl(x.w);
        P[i] = o;
    }
}

// ---------------- pack + transpose BOTH weights in one launch ----------------
__global__ void pack_wt_both(const float* __restrict__ W1, const float* __restrict__ W2,
                             uint32_t* __restrict__ Bt1, uint32_t* __restrict__ Bt2) {
    const int t1 = IN_F * H1_F;
    const int total = t1 + H1_F * H2_F;
    int stride = gridDim.x * blockDim.x;
    for (int idx = blockIdx.x * blockDim.x + threadIdx.x; idx < total; idx += stride) {
        if (idx < t1) {
            int k = idx / H1_F, n = idx - k * H1_F;
            Bt1[(size_t)n * IN_F + k] = pack_hl(W1[idx]);
        } else {
            int i2 = idx - t1;
            int k = i2 / H2_F, n = i2 - k * H2_F;
            Bt2[(size_t)n * H1_F + k] = pack_hl(W2[i2]);
        }
    }
}

// ---------------- split-bf16 MFMA GEMM (128x128 tile, BK=32, 4 waves) ----------------
// D = Am@Bm + Am@Br + Ar@Bm  (fp32-class accuracy). Writes bf16.
__device__ inline void split_frag(const u32x4& lo, const u32x4& hi,
                                  short8& mainf, short8& resf) {
    u32x4 mm, rr;
    mm.x = __builtin_amdgcn_perm(lo.y, lo.x, 0x05040100u);
    mm.y = __builtin_amdgcn_perm(lo.w, lo.z, 0x05040100u);
    mm.z = __builtin_amdgcn_perm(hi.y, hi.x, 0x05040100u);
    mm.w = __builtin_amdgcn_perm(hi.w, hi.z, 0x05040100u);
    rr.x = __builtin_amdgcn_perm(lo.y, lo.x, 0x07060302u);
    rr.y = __builtin_amdgcn_perm(lo.w, lo.z, 0x07060302u);
    rr.z = __builtin_amdgcn_perm(hi.y, hi.x, 0x07060302u);
    rr.w = __builtin_amdgcn_perm(hi.w, hi.z, 0x07060302u);
    mainf = __builtin_bit_cast(short8, mm);
    resf  = __builtin_bit_cast(short8, rr);
}

template <bool ROWSCALE>
__global__ __launch_bounds__(256, 1) void gemm_split(
        const uint32_t* __restrict__ Apk, const uint32_t* __restrict__ Btpk,
        __hip_bfloat16* __restrict__ Cout, const int* __restrict__ rowcnt,
        int M, int Nout, int K) {
    __shared__ uint32_t Al[128 * 32];
    __shared__ uint32_t Bl[128 * 32];
    const int tid = threadIdx.x;
    const int lane = tid & 63, wid = tid >> 6;
    const int wm = wid >> 1, wn = wid & 1;
    const int l15 = lane & 15, lhi = lane >> 4;
    const int brow = blockIdx.x * 128, bcol = blockIdx.y * 128;

    f32x4 acc[4][4];
#pragma unroll
    for (int m = 0; m < 4; ++m)
#pragma unroll
        for (int n = 0; n < 4; ++n) acc[m][n] = f32x4{0.f, 0.f, 0.f, 0.f};

    for (int k0 = 0; k0 < K; k0 += 32) {
#pragma unroll
        for (int i = 0; i < 4; ++i) {
            int chunk = i * 256 + tid;
            int r = chunk >> 3, c16 = chunk & 7;
            int c16s = c16 ^ (r & 7);
            gld_lds16(Apk + (size_t)(brow + r) * K + k0 + c16s * 4, Al + chunk * 4);
            gld_lds16(Btpk + (size_t)(bcol + r) * K + k0 + c16s * 4, Bl + chunk * 4);
        }
        __syncthreads();

        u32x4 apk[4][2], bpk[4][2];
#pragma unroll
        for (int m = 0; m < 4; ++m) {
            int row = wm * 64 + m * 16 + l15;
            const uint32_t* base = Al + row * 32;
            int rs = row & 7;
            apk[m][0] = *(const u32x4*)(base + (((lhi << 1) ^ rs) << 2));
            apk[m][1] = *(const u32x4*)(base + ((((lhi << 1) | 1) ^ rs) << 2));
        }
#pragma unroll
        for (int n = 0; n < 4; ++n) {
            int col = wn * 64 + n * 16 + l15;
            const uint32_t* base = Bl + col * 32;
            int rs = col & 7;
            bpk[n][0] = *(const u32x4*)(base + (((lhi << 1) ^ rs) << 2));
            bpk[n][1] = *(const u32x4*)(base + ((((lhi << 1) | 1) ^ rs) << 2));
        }
        short8 am[4], ar[4], bm[4], br[4];
#pragma unroll
        for (int m = 0; m < 4; ++m) split_frag(apk[m][0], apk[m][1], am[m], ar[m]);
#pragma unroll
        for (int n = 0; n < 4; ++n) split_frag(bpk[n][0], bpk[n][1], bm[n], br[n]);

#pragma unroll
        for (int m = 0; m < 4; ++m)
#pragma unroll
            for (int n = 0; n < 4; ++n) {
                f32x4 c = acc[m][n];
                c = __builtin_amdgcn_mfma_f32_16x16x32_bf16(ar[m], bm[n], c, 0, 0, 0);
                c = __builtin_amdgcn_mfma_f32_16x16x32_bf16(am[m], br[n], c, 0, 0, 0);
                c = __builtin_amdgcn_mfma_f32_16x16x32_bf16(am[m], bm[n], c, 0, 0, 0);
                acc[m][n] = c;
            }
        __syncthreads();
    }

    // epilogue: C/D layout col = lane&15, row = (lane>>4)*4 + j
#pragma unroll
    for (int m = 0; m < 4; ++m) {
        int rbase = brow + wm * 64 + m * 16 + lhi * 4;
        float scl[4];
#pragma unroll
        for (int j = 0; j < 4; ++j) {
            scl[j] = 1.f;
            if (ROWSCALE && rbase + j < M)
                scl[j] = rsqrtf(fmaxf((float)rowcnt[rbase + j], 1.f));
        }
#pragma unroll
        for (int n = 0; n < 4; ++n) {
            int col = bcol + wn * 64 + n * 16 + l15;
#pragma unroll
            for (int j = 0; j < 4; ++j) {
                int row = rbase + j;
                if (row < M)
                    Cout[(size_t)row * Nout + col] = __float2bfloat16(acc[m][n][j] * scl[j]);
            }
        }
    }
}

// ---------------- SpMM1: 8 edges in flight, uint4 gathers, 4 XCD-affine slices ----------------
__global__ void spmm1_g8(const uint4* __restrict__ h4,   // rows of 32 uint4 (256 bf16 feats)
                         const unsigned long long* __restrict__ s_pk,
                         const int* __restrict__ row_start, const int* __restrict__ in_cnt,
                         const float* __restrict__ b1, uint32_t* __restrict__ h1pk, int N) {
    int bx = blockIdx.x;
    int slice = bx & 3;              // XCD x serves slice x&3 only
    int grp = bx >> 2;
    int wid = threadIdx.x >> 6, lane = threadIdx.x & 63;
    int node = grp * 4 + wid;
    if (node >= N) return;
    int start = row_start[node], cnt = in_cnt[node];
    int el = lane >> 3, fo = lane & 7;
    const uint4* hb = h4 + slice * 8 + fo;
    float acc[8] = {};
    for (int j = el; j < cnt; j += 8) {
        unsigned long long m = s_pk[start + j];
        int s = (int)(unsigned)m;
        float w = __builtin_bit_cast(float, (unsigned)(m >> 32));
        uint4 v = hb[(size_t)s * 32];
        acc[0] = fmaf(w, bf_lo(v.x), acc[0]); acc[1] = fmaf(w, bf_hi(v.x), acc[1]);
        acc[2] = fmaf(w, bf_lo(v.y), acc[2]); acc[3] = fmaf(w, bf_hi(v.y), acc[3]);
        acc[4] = fmaf(w, bf_lo(v.z), acc[4]); acc[5] = fmaf(w, bf_hi(v.z), acc[5]);
        acc[6] = fmaf(w, bf_lo(v.w), acc[6]); acc[7] = fmaf(w, bf_hi(v.w), acc[7]);
    }
#pragma unroll
    for (int d = 8; d < 64; d <<= 1)
#pragma unroll
        for (int k = 0; k < 8; ++k) acc[k] += __shfl_xor(acc[k], d);
    if (el == 0) {
        int fi = slice * 64 + fo * 8;
        u32x4 o0, o1;
        o0.x = pack_hl(fmaxf(acc[0] + b1[fi + 0], 0.f));
        o0.y = pack_hl(fmaxf(acc[1] + b1[fi + 1], 0.f));
        o0.z = pack_hl(fmaxf(acc[2] + b1[fi + 2], 0.f));
        o0.w = pack_hl(fmaxf(acc[3] + b1[fi + 3], 0.f));
        o1.x = pack_hl(fmaxf(acc[4] + b1[fi + 4], 0.f));
        o1.y = pack_hl(fmaxf(acc[5] + b1[fi + 5], 0.f));
        o1.z = pack_hl(fmaxf(acc[6] + b1[fi + 6], 0.f));
        o1.w = pack_hl(fmaxf(acc[7] + b1[fi + 7], 0.f));
        uint32_t* dp = h1pk + (size_t)node * H1_F + fi;
        *(u32x4*)dp = o0;
        *(u32x4*)(dp + 4) = o1;
    }
}

// ---------------- SpMM2: 8 edges in flight, uint4 gathers, 2 XCD-affine slices ----------------
__global__ void spmm2_g8(const uint4* __restrict__ h4,   // rows of 16 uint4 (128 bf16 feats)
                         const unsigned long long* __restrict__ s_pk,
                         const int* __restrict__ row_start, const int* __restrict__ in_cnt,
                         const float* __restrict__ b2, float* __restrict__ out, int N) {
    int bx = blockIdx.x;
    int slice = bx & 1;
    int grp = bx >> 1;
    int wid = threadIdx.x >> 6, lane = threadIdx.x & 63;
    int node = grp * 4 + wid;
    if (node >= N) return;
    int start = row_start[node], cnt = in_cnt[node];
    int el = lane >> 3, fo = lane & 7;
    const uint4* hb = h4 + slice * 8 + fo;
    float acc[8] = {};
    for (int j = el; j < cnt; j += 8) {
        unsigned long long m = s_pk[start + j];
        int s = (int)(unsigned)m;
        uint4 v = hb[(size_t)s * 16];
        acc[0] += bf_lo(v.x); acc[1] += bf_hi(v.x);
        acc[2] += bf_lo(v.y); acc[3] += bf_hi(v.y);
        acc[4] += bf_lo(v.z); acc[5] += bf_hi(v.z);
        acc[6] += bf_lo(v.w); acc[7] += bf_hi(v.w);
    }
#pragma unroll
    for (int d = 8; d < 64; d <<= 1)
#pragma unroll
        for (int k = 0; k < 8; ++k) acc[k] += __shfl_xor(acc[k], d);
    if (el == 0) {
        float rin = rsqrtf(fmaxf((float)cnt, 1.f));
        int fi = slice * 64 + fo * 8;
        f32x4 r0, r1;
        r0.x = acc[0] * rin + b2[fi + 0];
        r0.y = acc[1] * rin + b2[fi + 1];
        r0.z = acc[2] * rin + b2[fi + 2];
        r0.w = acc[3] * rin + b2[fi + 3];
        r1.x = acc[4] * rin + b2[fi + 4];
        r1.y = acc[5] * rin + b2[fi + 5];
        r1.z = acc[6] * rin + b2[fi + 6];
        r1.w = acc[7] * rin + b2[fi + 7];
        float* dp = out + (size_t)node * H2_F + fi;
        *(f32x4*)dp = r0;
        *(f32x4*)(dp + 4) = r1;
    }
}

extern "C" void kernel_launch(void* const* d_in, const int* in_sizes, int n_in,
                              void* d_out, int out_size, void* d_ws, size_t ws_size,
                              hipStream_t stream) {
    const float* features = (const float*)d_in[0];
    const float* edge_w   = (const float*)d_in[1];
    const int*   src      = (const int*)d_in[2];
    const int*   dst      = (const int*)d_in[3];
    const float* W1       = (const float*)d_in[4];
    const float* b1       = (const float*)d_in[5];
    const float* W2       = (const float*)d_in[6];
    const float* b2       = (const float*)d_in[7];
    float* out = (float*)d_out;

    const int N = in_sizes[0] / IN_F;   // 20000
    const int E = in_sizes[1];          // 640000
    const int CH = (E + BH - 1) / BH;   // 5000 edges per histogram chunk

    char* base = (char*)d_ws;
    size_t off = 0;
    auto alloc = [&](size_t bytes) {
        char* p = base + off;
        off = (off + bytes + 255) & ~(size_t)255;
        return p;
    };
    int*   out_cnt   = (int*)  alloc((size_t)N * 4);
    float* out_rs    = (float*)alloc((size_t)N * 4);
    int*   in_cnt    = (int*)  alloc((size_t)N * 4);
    int*   row_start = (int*)  alloc((size_t)N * 4);
    unsigned long long* s_pk = (unsigned long long*)alloc((size_t)E * 8);
    uint32_t* Bt1    = (uint32_t*)alloc((size_t)H1_F * IN_F * 4);
    uint32_t* Bt2    = (uint32_t*)alloc((size_t)H2_F * H1_F * 4);
    __hip_bfloat16* h_bf = (__hip_bfloat16*)alloc((size_t)MPAD * H1_F * 2);
    uint32_t* Apk    = (uint32_t*)alloc((size_t)MPAD * IN_F * 4);   // 41.2 MB
    // ---- overlays inside Apk (all CSR temps dead before pack_rows writes Apk) ----
    uint32_t* Hd = Apk;                                   // [BH][NPAIR]      5.12 MB
    uint32_t* Od = Apk + (size_t)BH * NPAIR;              // [BH][NN]        10.24 MB
    uint32_t* Pc = Od + (size_t)BH * NN;                  // [2][BH][5000]    5.12 MB
    uint32_t* Pw = Pc + (size_t)2 * BH * 5000;            // [2][BH][NPAIR]  10.24 MB
    // later overlays (Apk dead after gemm1):
    uint32_t* h1pk = Apk;                                 // [MPAD][256] u32
    uint32_t* h2b  = Apk + (size_t)MPAD * H1_F;           // [MPAD][64] u32 of bf16x2
    (void)ws_size;

    // ---- CSR build + norms (no global atomics, no memsets) ----
    build_partials<<<BH, 256, 0, stream>>>(dst, src, edge_w, Hd, Pc, Pw, E, CH);
    offsets_kernel<<<(NPAIR + 255) / 256, 256, 0, stream>>>(
        Hd, (uint2*)Od, in_cnt, Pc, (const uint2*)Pw, out_cnt, out_rs);
    scan_kernel<<<1, 1024, 0, stream>>>(in_cnt, row_start, N);
    scatter_dst<<<BH, 256, 0, stream>>>(src, dst, edge_w, row_start, Od, s_pk, E, CH);
    in_finalize<<<N, 64, 0, stream>>>(out_rs, row_start, in_cnt, s_pk, N);

    // ---- operand packing ----
    pack_rows<<<2048, 256, 0, stream>>>((const float4*)features, (u32x4*)Apk, N * IN_F / 4);
    pack_wt_both<<<320, 256, 0, stream>>>(W1, W2, Bt1, Bt2);

    // ---- layer 1 ----
    dim3 g1(MPAD / 128, H1_F / 128);
    gemm_split<false><<<g1, 256, 0, stream>>>(Apk, Bt1, h_bf, nullptr, N, H1_F, IN_F);
    int grp = (N + 3) / 4;
    spmm1_g8<<<grp * 4, 256, 0, stream>>>((const uint4*)h_bf, s_pk,
                                          row_start, in_cnt, b1, h1pk, N);
    // ---- layer 2 ----
    dim3 g2(MPAD / 128, H2_F / 128);
    gemm_split<true><<<g2, 256, 0, stream>>>(h1pk, Bt2, (__hip_bfloat16*)h2b, out_cnt,
                                             N, H2_F, H1_F);
    spmm2_g8<<<grp * 2, 256, 0, stream>>>((const uint4*)h2b, s_pk,
                                          row_start, in_cnt, b2, out, N);
}